// Round 1
// 145.021 us; speedup vs baseline: 1.0216x; 1.0216x over previous
//
#include <hip/hip_runtime.h>
#include <hip/hip_bf16.h>

#define HEADS    8
#define HEAD_DIM 64
#define DIM      512
#define D_IN     256
#define BATCH    4
#define SEQ      2048
#define KNBR     32
#define ROWS     (BATCH*SEQ)     // 8192
#define NQKV     (3*DIM)         // 1536

typedef __hip_bfloat16 bf16;
typedef __attribute__((ext_vector_type(8))) short bf16x8;
typedef __attribute__((ext_vector_type(4))) float floatx4;

__device__ __forceinline__ ushort f2bf(float f) {
    union { bf16 h; ushort u; } c; c.h = __float2bfloat16(f); return c.u;
}

// 8 packed bf16 (16B) -> 8 floats
__device__ __forceinline__ void load_bf16x8(const bf16* p, float* o) {
    uint4 raw = *(const uint4*)p;
    unsigned u[4] = {raw.x, raw.y, raw.z, raw.w};
#pragma unroll
    for (int i = 0; i < 4; i++) {
        o[2*i]   = __uint_as_float(u[i] << 16);
        o[2*i+1] = __uint_as_float(u[i] & 0xffff0000u);
    }
}

__device__ __forceinline__ void async16(const bf16* g, bf16* l) {
    __builtin_amdgcn_global_load_lds(
        (const __attribute__((address_space(1))) void*)g,
        (__attribute__((address_space(3))) void*)l, 16, 0, 0);
}

// ---- fused prep: fp32->bf16 conversion of x/ctx + weight transpose + bias ----
__global__ __launch_bounds__(256)
void prep_kernel(const float* __restrict__ x, const float* __restrict__ ctx,
                 const float* __restrict__ Wq, const float* __restrict__ Wk,
                 const float* __restrict__ Wv, const float* __restrict__ Wo,
                 const float* __restrict__ bq,
                 bf16* __restrict__ xb, bf16* __restrict__ cb,
                 bf16* __restrict__ Wqkv, bf16* __restrict__ WoT,
                 float* __restrict__ biasq)
{
    const int b = blockIdx.x;
    if (b < 2048) {   // ---- conv: 8 fp32 -> 8 bf16 per thread
        const int gid  = b * 256 + threadIdx.x;
        const int half = (ROWS * D_IN) / 8;     // 262144
        const float* src; bf16* dst; int f;
        if (gid < half) { src = x;   dst = xb; f = gid * 8; }
        else            { src = ctx; dst = cb; f = (gid - half) * 8; }
        float4 v0 = *(const float4*)(src + f);
        float4 v1 = *(const float4*)(src + f + 4);
        uint4 o;
        o.x = f2bf(v0.x) | ((unsigned)f2bf(v0.y) << 16);
        o.y = f2bf(v0.z) | ((unsigned)f2bf(v0.w) << 16);
        o.z = f2bf(v1.x) | ((unsigned)f2bf(v1.y) << 16);
        o.w = f2bf(v1.z) | ((unsigned)f2bf(v1.w) << 16);
        *(uint4*)(dst + f) = o;
        return;
    }
    int p = b - 2048;
    if (p >= 512) {   // ---- bias: biasq[1536] = bq | 0 | 0
        int i = (p - 512) * 256 + threadIdx.x;
        if (i < NQKV) biasq[i] = (i < DIM) ? bq[i] : 0.f;
        return;
    }
    // ---- weight transpose tiles (32x32)
    __shared__ float tile[32][33];
    int z, tb;
    if (p < 384) { z = p >> 7; tb = p & 127; }
    else         { z = 3;      tb = p - 384; }
    const float* src; bf16* dst; int C, bx, by;
    if      (z == 0) { src = Wq; dst = Wqkv;              C = 512; }
    else if (z == 1) { src = Wk; dst = Wqkv + 512 * 256;  C = 512; }
    else if (z == 2) { src = Wv; dst = Wqkv + 1024 * 256; C = 512; }
    else             { src = Wo; dst = WoT;               C = 256; }
    if (z < 3) { bx = tb & 15; by = tb >> 4; }
    else       { bx = tb & 7;  by = tb >> 3; }
    const int r0 = by * 32, c0 = bx * 32;
    const int tx = threadIdx.x & 31, ty = threadIdx.x >> 5;
#pragma unroll
    for (int i = 0; i < 4; i++)
        tile[ty + 8*i][tx] = src[(size_t)(r0 + ty + 8*i) * C + c0 + tx];
    __syncthreads();
#pragma unroll
    for (int i = 0; i < 4; i++)
        dst[(size_t)(c0 + ty + 8*i) * ((z < 3) ? 256 : 512) + r0 + tx] =
            __float2bfloat16(tile[tx][ty + 8*i]);
}

// ---- MFMA GEMM: C[M][NN] = A[M][KD] @ B[NN][KD]^T (+bias) ----
// Compile-time K (full unroll), double-buffered LDS with prefetch-before-compute
// (one barrier per K-step; implicit vmcnt(0) drain at the barrier covers the
// prefetch issued at step start, overlapped with this step's MFMAs), and an
// LDS-staged epilogue producing 16B/lane coalesced C stores.
template<int TM, int TN, int KD, int NN, int CBF16>
__global__ __launch_bounds__(256)
void mfma_gemm(const bf16* __restrict__ A, const bf16* __restrict__ A2, int split,
               const bf16* __restrict__ B, const float* __restrict__ bias,
               void* __restrict__ C)
{
    constexpr int MI = TM / 32, NI = TN / 32;
    constexpr int NT = KD / 64;
    static_assert((TM * 64 + TN * 64) * 2 * 2 <= 65536, "LDS budget");
    __shared__ bf16 As[2][TM * 64];
    __shared__ bf16 Bs[2][TN * 64];
    const int t    = threadIdx.x;
    const int lane = t & 63;
    const int w    = t >> 6;
    const int row0 = blockIdx.y * TM;
    const int col0 = blockIdx.x * TN;
    const bf16* Au = (col0 < split) ? A : A2;
    const int wm   = (w >> 1) * (TM / 2);
    const int wn   = (w & 1) * (TN / 2);

    const int sr = t >> 3;          // 0..31
    const int sc = (t & 7) * 8;     // bf16 elem offset of 16B chunk

    floatx4 acc[MI][NI];
#pragma unroll
    for (int i = 0; i < MI; i++)
#pragma unroll
        for (int j = 0; j < NI; j++) acc[i][j] = (floatx4){0.f, 0.f, 0.f, 0.f};

    const int fr = lane & 15;
    const int fq = lane >> 4;

    auto stage = [&](int buf, int k0) {
#pragma unroll
        for (int is = 0; is < TM / 32; is++)
            async16(Au + (size_t)(row0 + is*32 + sr) * KD + k0 + sc,
                    &As[buf][is*2048 + w*512]);
#pragma unroll
        for (int is = 0; is < TN / 32; is++)
            async16(B + (size_t)(col0 + is*32 + sr) * KD + k0 + sc,
                    &Bs[buf][is*2048 + w*512]);
    };

    stage(0, 0);
    __syncthreads();                 // implicit vmcnt(0): buf0 ready

#pragma unroll
    for (int tt = 0; tt < NT; ++tt) {
        const int cur = tt & 1;
        if (tt + 1 < NT) stage(cur ^ 1, (tt + 1) * 64);   // prefetch in flight
#pragma unroll
        for (int ks = 0; ks < 2; ks++) {
            bf16x8 af[MI], bfr[NI];
#pragma unroll
            for (int mi = 0; mi < MI; mi++)
                af[mi] = *(const bf16x8*)&As[cur][(wm + mi*16 + fr) * 64 + ks*32 + fq*8];
#pragma unroll
            for (int ni = 0; ni < NI; ni++)
                bfr[ni] = *(const bf16x8*)&Bs[cur][(wn + ni*16 + fr) * 64 + ks*32 + fq*8];
#pragma unroll
            for (int mi = 0; mi < MI; mi++)
#pragma unroll
                for (int ni = 0; ni < NI; ni++)
                    acc[mi][ni] = __builtin_amdgcn_mfma_f32_16x16x32_bf16(
                        af[mi], bfr[ni], acc[mi][ni], 0, 0, 0);
        }
        __syncthreads();             // drains prefetch + guards buffer reuse
    }

    // ---- epilogue: stage per-wave [16][WN] f32 tile in LDS, re-read coalesced.
    // Last __syncthreads() above guarantees all waves finished ds_reads of As/Bs.
    constexpr int WN  = NI * 16;          // wave n-extent (64 or 32)
    constexpr int STR = WN + 4;           // f32 row stride (16B-aligned rows)
    float* wep = (float*)As + w * (16 * STR);   // wave-private region (fits in As)

#pragma unroll
    for (int mi = 0; mi < MI; mi++) {
#pragma unroll
        for (int ni = 0; ni < NI; ni++) {
            const float bv = bias[col0 + wn + ni*16 + fr];
#pragma unroll
            for (int r = 0; r < 4; r++)
                wep[(fq*4 + r) * STR + ni*16 + fr] = acc[mi][ni][r] + bv;
        }
        if constexpr (CBF16) {
            constexpr int LPR = WN / 8;   // lanes per row (8 f32 -> 8 bf16 each)
            constexpr int RPP = 64 / LPR; // rows per pass
            constexpr int NP  = 16 / RPP; // passes
#pragma unroll
            for (int p = 0; p < NP; p++) {
                const int rl = p * RPP + lane / LPR;
                const int cl = (lane % LPR) * 8;
                const float4 a  = *(const float4*)&wep[rl * STR + cl];
                const float4 b2 = *(const float4*)&wep[rl * STR + cl + 4];
                uint4 o;
                o.x = f2bf(a.x)  | ((unsigned)f2bf(a.y)  << 16);
                o.y = f2bf(a.z)  | ((unsigned)f2bf(a.w)  << 16);
                o.z = f2bf(b2.x) | ((unsigned)f2bf(b2.y) << 16);
                o.w = f2bf(b2.z) | ((unsigned)f2bf(b2.w) << 16);
                *(uint4*)((bf16*)C + (size_t)(row0 + wm + mi*16 + rl) * NN
                                   + col0 + wn + cl) = o;
            }
        } else {
            constexpr int LPR = WN / 4;   // lanes per row (float4 each)
            constexpr int RPP = 64 / LPR;
            constexpr int NP  = 16 / RPP;
#pragma unroll
            for (int p = 0; p < NP; p++) {
                const int rl = p * RPP + lane / LPR;
                const int cl = (lane % LPR) * 4;
                const float4 a = *(const float4*)&wep[rl * STR + cl];
                *(float4*)((float*)C + (size_t)(row0 + wm + mi*16 + rl) * NN
                                     + col0 + wn + cl) = a;
            }
        }
    }
}

// ---- fused gather-attention: one wave per query, wave-private LDS, no barriers ----
__global__ __launch_bounds__(256, 4)
void attn_kernel(const bf16* __restrict__ qkv, const int* __restrict__ idx,
                 bf16* __restrict__ att)
{
    __shared__ int   s_off[4][KNBR];
    __shared__ float s_part[4][16][68];
    __shared__ float s_aw[4][KNBR][HEADS];

    const int t    = threadIdx.x;
    const int w    = t >> 6;
    const int lane = t & 63;
    const int i    = blockIdx.x;
    const int batch  = (i >> 1) & 3;
    const int within = ((i >> 3) << 1) | (i & 1);
    const int bn     = batch * SEQ + within * 4 + w;

    int* woff = s_off[w];
    float (*wpart)[68] = s_part[w];
    float* waw = &s_aw[w][0][0];

    if (lane < KNBR) woff[lane] = idx[(size_t)bn * KNBR + lane] * (NQKV * 2);

    float qr[8];
    load_bf16x8(qkv + (size_t)bn * NQKV + lane * 8, qr);

    const char* kbase = (const char*)qkv +
        ((size_t)batch * SEQ * NQKV + DIM) * 2 + lane * 16;
    const int h = lane >> 3;

    float sim[4];
#pragma unroll
    for (int pass = 0; pass < 2; pass++) {
#pragma unroll 8
        for (int kk = 0; kk < 16; kk++) {
            const int off = woff[pass * 16 + kk];
            float k8[8];
            load_bf16x8((const bf16*)(kbase + off), k8);
            float d = 0.f;
#pragma unroll
            for (int e = 0; e < 8; e++) d += qr[e] * k8[e];
            wpart[kk][lane] = d;
        }
#pragma unroll
        for (int r = 0; r < 2; r++) {
            const int p = lane + 64 * r;
            const float4* pp = (const float4*)&wpart[p >> 3][(p & 7) * 8];
            float4 a = pp[0], b2 = pp[1];
            sim[pass*2 + r] = (a.x + a.y + a.z + a.w + b2.x + b2.y + b2.z + b2.w) * 0.125f;
        }
    }

    float mx = fmaxf(fmaxf(sim[0], sim[1]), fmaxf(sim[2], sim[3]));
    mx = fmaxf(mx, __shfl_xor(mx, 8));
    mx = fmaxf(mx, __shfl_xor(mx, 16));
    mx = fmaxf(mx, __shfl_xor(mx, 32));
    float e4[4], ss = 0.f;
#pragma unroll
    for (int r = 0; r < 4; r++) { e4[r] = __expf(sim[r] - mx); ss += e4[r]; }
    ss += __shfl_xor(ss, 8);
    ss += __shfl_xor(ss, 16);
    ss += __shfl_xor(ss, 32);
    const float inv = 1.f / ss;
    const int kk0 = lane >> 3, hh = lane & 7;
#pragma unroll
    for (int r = 0; r < 4; r++) waw[(kk0 + 8*r) * HEADS + hh] = e4[r] * inv;

    float acc[8] = {};
#pragma unroll 8
    for (int kk = 0; kk < KNBR; kk++) {
        const int off = woff[kk];
        const float a = waw[kk * HEADS + h];
        float v8[8];
        load_bf16x8((const bf16*)(kbase + off + DIM * 2), v8);
#pragma unroll
        for (int e = 0; e < 8; e++) acc[e] += a * v8[e];
    }

    uint4 o;
    o.x = f2bf(acc[0]) | ((unsigned)f2bf(acc[1]) << 16);
    o.y = f2bf(acc[2]) | ((unsigned)f2bf(acc[3]) << 16);
    o.z = f2bf(acc[4]) | ((unsigned)f2bf(acc[5]) << 16);
    o.w = f2bf(acc[6]) | ((unsigned)f2bf(acc[7]) << 16);
    *(uint4*)(att + (size_t)bn * DIM + lane * 8) = o;
}

extern "C" void kernel_launch(void* const* d_in, const int* in_sizes, int n_in,
                              void* d_out, int out_size, void* d_ws, size_t ws_size,
                              hipStream_t stream)
{
    const float* x    = (const float*)d_in[0];
    const float* ctx  = (const float*)d_in[1];
    const int*   idx  = (const int*)d_in[2];
    const float* Wq   = (const float*)d_in[5];
    const float* bq   = (const float*)d_in[6];
    const float* Wk   = (const float*)d_in[7];
    const float* Wv   = (const float*)d_in[8];
    const float* Wout = (const float*)d_in[9];
    const float* bout = (const float*)d_in[10];

    char*  ws    = (char*)d_ws;
    bf16*  xb    = (bf16*)(ws);                                   //  4 MB
    bf16*  cb    = (bf16*)(ws + (size_t) 4*1024*1024);            //  4 MB
    bf16*  Wqkv  = (bf16*)(ws + (size_t) 8*1024*1024);            // 768 KB
    bf16*  WoT   = (bf16*)(ws + (size_t) 9*1024*1024);            // 256 KB
    float* biasq = (float*)(ws + (size_t) 9*1024*1024 + 524288);  //   6 KB
    bf16*  Cqkv  = (bf16*)(ws + (size_t)10*1024*1024);            //  24 MB
    bf16*  atb   = (bf16*)(ws + (size_t)34*1024*1024);            //   8 MB

    prep_kernel<<<dim3(2048 + 512 + 6), dim3(256), 0, stream>>>(
        x, ctx, Wq, Wk, Wv, Wout, bq, xb, cb, Wqkv, WoT, biasq);
    mfma_gemm<128,128,256,1536,1><<<dim3(12, 64), dim3(256), 0, stream>>>(
        xb, cb, 512, Wqkv, biasq, Cqkv);
    attn_kernel<<<dim3(2048), dim3(256), 0, stream>>>(Cqkv, idx, atb);
    mfma_gemm<64,64,512,256,0><<<dim3(4, 128), dim3(256), 0, stream>>>(
        atb, atb, 1 << 30, WoT, bout, d_out);
}

// Round 2
// 143.654 us; speedup vs baseline: 1.0313x; 1.0095x over previous
//
#include <hip/hip_runtime.h>
#include <hip/hip_bf16.h>

#define HEADS    8
#define HEAD_DIM 64
#define DIM      512
#define D_IN     256
#define BATCH    4
#define SEQ      2048
#define KNBR     32
#define ROWS     (BATCH*SEQ)     // 8192
#define NQKV     (3*DIM)         // 1536

typedef __hip_bfloat16 bf16;
typedef __attribute__((ext_vector_type(8))) short bf16x8;
typedef __attribute__((ext_vector_type(4))) float floatx4;

__device__ __forceinline__ ushort f2bf(float f) {
    union { bf16 h; ushort u; } c; c.h = __float2bfloat16(f); return c.u;
}

// 8 packed bf16 (16B) -> 8 floats
__device__ __forceinline__ void load_bf16x8(const bf16* p, float* o) {
    uint4 raw = *(const uint4*)p;
    unsigned u[4] = {raw.x, raw.y, raw.z, raw.w};
#pragma unroll
    for (int i = 0; i < 4; i++) {
        o[2*i]   = __uint_as_float(u[i] << 16);
        o[2*i+1] = __uint_as_float(u[i] & 0xffff0000u);
    }
}

__device__ __forceinline__ void async16(const bf16* g, bf16* l) {
    __builtin_amdgcn_global_load_lds(
        (const __attribute__((address_space(1))) void*)g,
        (__attribute__((address_space(3))) void*)l, 16, 0, 0);
}

// ---- fused prep: fp32->bf16 conversion of x/ctx + weight transpose + bias ----
__global__ __launch_bounds__(256)
void prep_kernel(const float* __restrict__ x, const float* __restrict__ ctx,
                 const float* __restrict__ Wq, const float* __restrict__ Wk,
                 const float* __restrict__ Wv, const float* __restrict__ Wo,
                 const float* __restrict__ bq,
                 bf16* __restrict__ xb, bf16* __restrict__ cb,
                 bf16* __restrict__ Wqkv, bf16* __restrict__ WoT,
                 float* __restrict__ biasq)
{
    const int b = blockIdx.x;
    if (b < 2048) {   // ---- conv: 8 fp32 -> 8 bf16 per thread
        const int gid  = b * 256 + threadIdx.x;
        const int half = (ROWS * D_IN) / 8;     // 262144
        const float* src; bf16* dst; int f;
        if (gid < half) { src = x;   dst = xb; f = gid * 8; }
        else            { src = ctx; dst = cb; f = (gid - half) * 8; }
        float4 v0 = *(const float4*)(src + f);
        float4 v1 = *(const float4*)(src + f + 4);
        uint4 o;
        o.x = f2bf(v0.x) | ((unsigned)f2bf(v0.y) << 16);
        o.y = f2bf(v0.z) | ((unsigned)f2bf(v0.w) << 16);
        o.z = f2bf(v1.x) | ((unsigned)f2bf(v1.y) << 16);
        o.w = f2bf(v1.z) | ((unsigned)f2bf(v1.w) << 16);
        *(uint4*)(dst + f) = o;
        return;
    }
    int p = b - 2048;
    if (p >= 512) {   // ---- bias: biasq[1536] = bq | 0 | 0
        int i = (p - 512) * 256 + threadIdx.x;
        if (i < NQKV) biasq[i] = (i < DIM) ? bq[i] : 0.f;
        return;
    }
    // ---- weight transpose tiles (32x32)
    __shared__ float tile[32][33];
    int z, tb;
    if (p < 384) { z = p >> 7; tb = p & 127; }
    else         { z = 3;      tb = p - 384; }
    const float* src; bf16* dst; int C, bx, by;
    if      (z == 0) { src = Wq; dst = Wqkv;              C = 512; }
    else if (z == 1) { src = Wk; dst = Wqkv + 512 * 256;  C = 512; }
    else if (z == 2) { src = Wv; dst = Wqkv + 1024 * 256; C = 512; }
    else             { src = Wo; dst = WoT;               C = 256; }
    if (z < 3) { bx = tb & 15; by = tb >> 4; }
    else       { bx = tb & 7;  by = tb >> 3; }
    const int r0 = by * 32, c0 = bx * 32;
    const int tx = threadIdx.x & 31, ty = threadIdx.x >> 5;
#pragma unroll
    for (int i = 0; i < 4; i++)
        tile[ty + 8*i][tx] = src[(size_t)(r0 + ty + 8*i) * C + c0 + tx];
    __syncthreads();
#pragma unroll
    for (int i = 0; i < 4; i++)
        dst[(size_t)(c0 + ty + 8*i) * ((z < 3) ? 256 : 512) + r0 + tx] =
            __float2bfloat16(tile[tx][ty + 8*i]);
}

// ---- MFMA GEMM (QKV): C[M][NN] = A[M][KD] @ B[NN][KD]^T (+bias) ----
// Double-buffered LDS, one barrier per K-step, LDS-staged coalesced epilogue.
template<int TM, int TN, int KD, int NN, int CBF16>
__global__ __launch_bounds__(256)
void mfma_gemm(const bf16* __restrict__ A, const bf16* __restrict__ A2, int split,
               const bf16* __restrict__ B, const float* __restrict__ bias,
               void* __restrict__ C)
{
    constexpr int MI = TM / 32, NI = TN / 32;
    constexpr int NT = KD / 64;
    __shared__ bf16 As[2][TM * 64];
    __shared__ bf16 Bs[2][TN * 64];
    const int t    = threadIdx.x;
    const int lane = t & 63;
    const int w    = t >> 6;
    const int row0 = blockIdx.y * TM;
    const int col0 = blockIdx.x * TN;
    const bf16* Au = (col0 < split) ? A : A2;
    const int wm   = (w >> 1) * (TM / 2);
    const int wn   = (w & 1) * (TN / 2);

    const int sr = t >> 3;          // 0..31
    const int sc = (t & 7) * 8;     // bf16 elem offset of 16B chunk

    floatx4 acc[MI][NI];
#pragma unroll
    for (int i = 0; i < MI; i++)
#pragma unroll
        for (int j = 0; j < NI; j++) acc[i][j] = (floatx4){0.f, 0.f, 0.f, 0.f};

    const int fr = lane & 15;
    const int fq = lane >> 4;

    auto stage = [&](int buf, int k0) {
#pragma unroll
        for (int is = 0; is < TM / 32; is++)
            async16(Au + (size_t)(row0 + is*32 + sr) * KD + k0 + sc,
                    &As[buf][is*2048 + w*512]);
#pragma unroll
        for (int is = 0; is < TN / 32; is++)
            async16(B + (size_t)(col0 + is*32 + sr) * KD + k0 + sc,
                    &Bs[buf][is*2048 + w*512]);
    };

    stage(0, 0);
    __syncthreads();

#pragma unroll
    for (int tt = 0; tt < NT; ++tt) {
        const int cur = tt & 1;
        if (tt + 1 < NT) stage(cur ^ 1, (tt + 1) * 64);
#pragma unroll
        for (int ks = 0; ks < 2; ks++) {
            bf16x8 af[MI], bfr[NI];
#pragma unroll
            for (int mi = 0; mi < MI; mi++)
                af[mi] = *(const bf16x8*)&As[cur][(wm + mi*16 + fr) * 64 + ks*32 + fq*8];
#pragma unroll
            for (int ni = 0; ni < NI; ni++)
                bfr[ni] = *(const bf16x8*)&Bs[cur][(wn + ni*16 + fr) * 64 + ks*32 + fq*8];
#pragma unroll
            for (int mi = 0; mi < MI; mi++)
#pragma unroll
                for (int ni = 0; ni < NI; ni++)
                    acc[mi][ni] = __builtin_amdgcn_mfma_f32_16x16x32_bf16(
                        af[mi], bfr[ni], acc[mi][ni], 0, 0, 0);
        }
        __syncthreads();
    }

    // ---- epilogue: stage per-wave [16][WN] f32 tile in LDS, re-read coalesced.
    constexpr int WN  = NI * 16;
    constexpr int STR = WN + 4;
    float* wep = (float*)As + w * (16 * STR);

#pragma unroll
    for (int mi = 0; mi < MI; mi++) {
#pragma unroll
        for (int ni = 0; ni < NI; ni++) {
            const float bv = bias[col0 + wn + ni*16 + fr];
#pragma unroll
            for (int r = 0; r < 4; r++)
                wep[(fq*4 + r) * STR + ni*16 + fr] = acc[mi][ni][r] + bv;
        }
        if constexpr (CBF16) {
            constexpr int LPR = WN / 8;
            constexpr int RPP = 64 / LPR;
            constexpr int NP  = 16 / RPP;
#pragma unroll
            for (int p = 0; p < NP; p++) {
                const int rl = p * RPP + lane / LPR;
                const int cl = (lane % LPR) * 8;
                const float4 a  = *(const float4*)&wep[rl * STR + cl];
                const float4 b2 = *(const float4*)&wep[rl * STR + cl + 4];
                uint4 o;
                o.x = f2bf(a.x)  | ((unsigned)f2bf(a.y)  << 16);
                o.y = f2bf(a.z)  | ((unsigned)f2bf(a.w)  << 16);
                o.z = f2bf(b2.x) | ((unsigned)f2bf(b2.y) << 16);
                o.w = f2bf(b2.z) | ((unsigned)f2bf(b2.w) << 16);
                *(uint4*)((bf16*)C + (size_t)(row0 + wm + mi*16 + rl) * NN
                                   + col0 + wn + cl) = o;
            }
        } else {
            constexpr int LPR = WN / 4;
            constexpr int RPP = 64 / LPR;
            constexpr int NP  = 16 / RPP;
#pragma unroll
            for (int p = 0; p < NP; p++) {
                const int rl = p * RPP + lane / LPR;
                const int cl = (lane % LPR) * 4;
                const float4 a = *(const float4*)&wep[rl * STR + cl];
                *(float4*)((float*)C + (size_t)(row0 + wm + mi*16 + rl) * NN
                                     + col0 + wn + cl) = a;
            }
        }
    }
}

// ---- fused gather-attention + output projection ----
// 512 blocks x 512 threads (8 waves). Each wave: 2 queries, full gather-attn
// (identical math to previous attn_kernel), att rows -> LDS (bf16, like the
// old atb roundtrip but on-chip). Then one barrier and a 16x256x512 MFMA
// out-projection against WoT (L2-hot, 256 KB), coalesced fp32 stores.
__global__ __launch_bounds__(512, 4)
void attn_out_kernel(const bf16* __restrict__ qkv, const int* __restrict__ idx,
                     const bf16* __restrict__ WoT, const float* __restrict__ bout,
                     float* __restrict__ outp)
{
    __shared__ int   s_off[8][KNBR];        //  1 KB
    __shared__ float s_part[8][16][68];     // 34.8 KB
    __shared__ float s_aw[8][KNBR][HEADS];  //  8 KB
    __shared__ bf16  s_att[16][520];        // 16.25 KB (pad: 2-way-max on reads)
    __shared__ float s_out[16][260];        // 16.25 KB

    const int t    = threadIdx.x;
    const int w    = t >> 6;
    const int lane = t & 63;
    const int i    = blockIdx.x;            // 0..511
    // XCD swizzle: i%8 -> XCD; XCDs {0,1}->batch0, {2,3}->b1, ... (L2 locality)
    const int batch  = (i >> 1) & 3;
    const int within = ((i >> 3) << 1) | (i & 1);  // 0..127
    const int q0     = batch * SEQ + within * 16;  // block's 16 queries

    int* woff = s_off[w];
    float (*wpart)[68] = s_part[w];
    float* waw = &s_aw[w][0][0];

    const char* kbase = (const char*)qkv +
        ((size_t)batch * SEQ * NQKV + DIM) * 2 + lane * 16;
    const int h = lane >> 3;

#pragma unroll
    for (int sub = 0; sub < 2; sub++) {
        const int qloc = w * 2 + sub;
        const int q    = q0 + qloc;

        if (lane < KNBR) woff[lane] = idx[(size_t)q * KNBR + lane] * (NQKV * 2);

        float qr[8];
        load_bf16x8(qkv + (size_t)q * NQKV + lane * 8, qr);

        // --- QK^T: per-lane partial dots -> LDS, reduce in slices ---
        float sim[4];
#pragma unroll
        for (int pass = 0; pass < 2; pass++) {
#pragma unroll 8
            for (int kk = 0; kk < 16; kk++) {
                const int off = woff[pass * 16 + kk];
                float k8[8];
                load_bf16x8((const bf16*)(kbase + off), k8);
                float d = 0.f;
#pragma unroll
                for (int e = 0; e < 8; e++) d += qr[e] * k8[e];
                wpart[kk][lane] = d;
            }
#pragma unroll
            for (int r = 0; r < 2; r++) {
                const int p = lane + 64 * r;
                const float4* pp = (const float4*)&wpart[p >> 3][(p & 7) * 8];
                float4 a = pp[0], b2 = pp[1];
                sim[pass*2 + r] = (a.x + a.y + a.z + a.w + b2.x + b2.y + b2.z + b2.w) * 0.125f;
            }
        }

        // --- softmax over 32 neighbors per head ---
        float mx = fmaxf(fmaxf(sim[0], sim[1]), fmaxf(sim[2], sim[3]));
        mx = fmaxf(mx, __shfl_xor(mx, 8));
        mx = fmaxf(mx, __shfl_xor(mx, 16));
        mx = fmaxf(mx, __shfl_xor(mx, 32));
        float e4[4], ss = 0.f;
#pragma unroll
        for (int r = 0; r < 4; r++) { e4[r] = __expf(sim[r] - mx); ss += e4[r]; }
        ss += __shfl_xor(ss, 8);
        ss += __shfl_xor(ss, 16);
        ss += __shfl_xor(ss, 32);
        const float inv = 1.f / ss;
        const int kk0 = lane >> 3, hh = lane & 7;
#pragma unroll
        for (int r = 0; r < 4; r++) waw[(kk0 + 8*r) * HEADS + hh] = e4[r] * inv;

        // --- PV ---
        float acc[8] = {};
#pragma unroll 8
        for (int kk = 0; kk < KNBR; kk++) {
            const int off = woff[kk];
            const float a = waw[kk * HEADS + h];
            float v8[8];
            load_bf16x8((const bf16*)(kbase + off + DIM * 2), v8);
#pragma unroll
            for (int e = 0; e < 8; e++) acc[e] += a * v8[e];
        }

        uint4 o;
        o.x = f2bf(acc[0]) | ((unsigned)f2bf(acc[1]) << 16);
        o.y = f2bf(acc[2]) | ((unsigned)f2bf(acc[3]) << 16);
        o.z = f2bf(acc[4]) | ((unsigned)f2bf(acc[5]) << 16);
        o.w = f2bf(acc[6]) | ((unsigned)f2bf(acc[7]) << 16);
        *(uint4*)&s_att[qloc][lane * 8] = o;
    }
    __syncthreads();

    // --- phase 2: out[16][256] = att[16][512] @ WoT[256][512]^T, MFMA ---
    const int fr = lane & 15, fq = lane >> 4;
    const int wn = w * 32;                   // wave's 32 output cols
    floatx4 o0 = (floatx4){0.f,0.f,0.f,0.f};
    floatx4 o1 = (floatx4){0.f,0.f,0.f,0.f};
#pragma unroll
    for (int ks = 0; ks < 16; ks++) {
        bf16x8 af = *(const bf16x8*)&s_att[fr][ks*32 + fq*8];
        bf16x8 b0 = *(const bf16x8*)&WoT[(size_t)(wn      + fr) * DIM + ks*32 + fq*8];
        bf16x8 b1 = *(const bf16x8*)&WoT[(size_t)(wn + 16 + fr) * DIM + ks*32 + fq*8];
        o0 = __builtin_amdgcn_mfma_f32_16x16x32_bf16(af, b0, o0, 0, 0, 0);
        o1 = __builtin_amdgcn_mfma_f32_16x16x32_bf16(af, b1, o1, 0, 0, 0);
    }
    // D layout: col = lane&15, row = (lane>>4)*4 + r  (row = att-row = qloc)
#pragma unroll
    for (int r = 0; r < 4; r++) {
        s_out[fq*4 + r][wn      + fr] = o0[r];
        s_out[fq*4 + r][wn + 16 + fr] = o1[r];
    }
    __syncthreads();

    // --- coalesced fp32 store: 512 threads x 8 floats = [16][256] ---
    const int row = t >> 5;
    const int col = (t & 31) * 8;
    float4 a  = *(const float4*)&s_out[row][col];
    float4 b2 = *(const float4*)&s_out[row][col + 4];
    const float4 ba = *(const float4*)&bout[col];
    const float4 bb = *(const float4*)&bout[col + 4];
    a.x += ba.x; a.y += ba.y; a.z += ba.z; a.w += ba.w;
    b2.x += bb.x; b2.y += bb.y; b2.z += bb.z; b2.w += bb.w;
    *(float4*)(outp + (size_t)(q0 + row) * D_IN + col)     = a;
    *(float4*)(outp + (size_t)(q0 + row) * D_IN + col + 4) = b2;
}

extern "C" void kernel_launch(void* const* d_in, const int* in_sizes, int n_in,
                              void* d_out, int out_size, void* d_ws, size_t ws_size,
                              hipStream_t stream)
{
    const float* x    = (const float*)d_in[0];
    const float* ctx  = (const float*)d_in[1];
    const int*   idx  = (const int*)d_in[2];
    const float* Wq   = (const float*)d_in[5];
    const float* bq   = (const float*)d_in[6];
    const float* Wk   = (const float*)d_in[7];
    const float* Wv   = (const float*)d_in[8];
    const float* Wout = (const float*)d_in[9];
    const float* bout = (const float*)d_in[10];

    char*  ws    = (char*)d_ws;
    bf16*  xb    = (bf16*)(ws);                                   //  4 MB
    bf16*  cb    = (bf16*)(ws + (size_t) 4*1024*1024);            //  4 MB
    bf16*  Wqkv  = (bf16*)(ws + (size_t) 8*1024*1024);            // 768 KB
    bf16*  WoT   = (bf16*)(ws + (size_t) 9*1024*1024);            // 256 KB
    float* biasq = (float*)(ws + (size_t) 9*1024*1024 + 524288);  //   6 KB
    bf16*  Cqkv  = (bf16*)(ws + (size_t)10*1024*1024);            //  24 MB

    // 1) convert inputs + transpose weights + bias
    prep_kernel<<<dim3(2048 + 512 + 6), dim3(256), 0, stream>>>(
        x, ctx, Wq, Wk, Wv, Wout, bq, xb, cb, Wqkv, WoT, biasq);
    // 2) [q|k|v] = [x|ctx] @ Wqkv^T
    mfma_gemm<128,128,256,1536,1><<<dim3(12, 64), dim3(256), 0, stream>>>(
        xb, cb, 512, Wqkv, biasq, Cqkv);
    // 3) fused gather attention + out-projection -> fp32 d_out
    attn_out_kernel<<<dim3(512), dim3(512), 0, stream>>>(
        Cqkv, idx, WoT, bout, (float*)d_out);
}